// Round 1
// baseline (841.517 us; speedup 1.0000x reference)
//
#include <hip/hip_runtime.h>
#include <math.h>

#define NN 8192
#define FF 256
#define ALPHA 0.2f

// ---------------- K1: h = X @ W  (256 blocks x 256 thr, 32 rows/block) ----
__global__ __launch_bounds__(256) void k1_xw(const float* __restrict__ X,
                                             const float* __restrict__ W,
                                             float* __restrict__ h) {
    __shared__ float xs[32][FF];
    const int t = threadIdx.x;
    const int i0 = blockIdx.x * 32;
    #pragma unroll
    for (int it = 0; it < 8; ++it) {
        int f = it * 256 + t;
        int r = f >> 6;
        int c4 = (f & 63) << 2;
        *(float4*)&xs[r][c4] = *(const float4*)&X[(size_t)(i0 + r) * FF + c4];
    }
    __syncthreads();
    float acc[32];
    #pragma unroll
    for (int r = 0; r < 32; ++r) acc[r] = 0.f;
    for (int kt = 0; kt < FF; kt += 8) {
        float wk[8];
        #pragma unroll
        for (int u = 0; u < 8; ++u) wk[u] = W[(size_t)(kt + u) * FF + t];
        #pragma unroll
        for (int r = 0; r < 32; ++r) {
            float4 xa = *(float4*)&xs[r][kt];
            float4 xb = *(float4*)&xs[r][kt + 4];
            acc[r] += xa.x * wk[0] + xa.y * wk[1] + xa.z * wk[2] + xa.w * wk[3]
                    + xb.x * wk[4] + xb.y * wk[5] + xb.z * wk[6] + xb.w * wk[7];
        }
    }
    #pragma unroll
    for (int r = 0; r < 32; ++r) h[(size_t)(i0 + r) * FF + t] = acc[r];
}

// ---------------- K2: src_i = h_i . a[:F], dst_i = h_i . a[F:] ------------
__global__ __launch_bounds__(256) void k2_srcdst(const float* __restrict__ h,
                                                 const float* __restrict__ a,
                                                 float* __restrict__ src,
                                                 float* __restrict__ dst) {
    const int wv = threadIdx.x >> 6;
    const int l = threadIdx.x & 63;
    const int i = blockIdx.x * 4 + wv;
    float s = 0.f, d = 0.f;
    #pragma unroll
    for (int k = 0; k < 4; ++k) {
        float hv = h[(size_t)i * FF + l + 64 * k];
        s += hv * a[l + 64 * k];
        d += hv * a[FF + l + 64 * k];
    }
    #pragma unroll
    for (int off = 32; off > 0; off >>= 1) {
        s += __shfl_down(s, off);
        d += __shfl_down(d, off);
    }
    if (l == 0) { src[i] = s; dst[i] = d; }
}

// ---------------- K2b: maxd = max_j dst_j (single block) ------------------
__global__ __launch_bounds__(256) void k2b_max(const float* __restrict__ dst,
                                               float* __restrict__ maxd) {
    __shared__ float red[256];
    float m = -1e30f;
    for (int i = threadIdx.x; i < NN; i += 256) m = fmaxf(m, dst[i]);
    red[threadIdx.x] = m;
    __syncthreads();
    for (int s = 128; s > 0; s >>= 1) {
        if (threadIdx.x < s) red[threadIdx.x] = fmaxf(red[threadIdx.x], red[threadIdx.x + s]);
        __syncthreads();
    }
    if (threadIdx.x == 0) maxd[0] = red[0];
}

// ---------------- K3: fused masked-softmax-weighted GEMM ------------------
// grid = (N/64) * S blocks, 256 threads. Each block: 64 rows x one j-segment.
// Produces partial num[seg][i][c] and den[seg][i].
__global__ __launch_bounds__(256) void k3_attn(const int* __restrict__ adj,
                                               const float* __restrict__ h,
                                               const float* __restrict__ src,
                                               const float* __restrict__ dst,
                                               const float* __restrict__ maxd,
                                               float* __restrict__ num,
                                               float* __restrict__ den,
                                               int S) {
    __shared__ float hs[32][FF];     // h tile   [j][c]   32 KB
    __shared__ float wT[32][64];     // weights  [j][r]    8 KB
    __shared__ float dl[64][4];      // den partials       1 KB
    const int t = threadIdx.x;
    const int nIt = NN / 64;         // 128 I-tiles
    const int it = blockIdx.x % nIt;
    const int seg = blockIdx.x / nIt;
    const int i0 = it * 64;
    const int jseg = NN / S;
    const int jbeg = seg * jseg;
    const int l = t & 63, wv = t >> 6;
    const int wr = t >> 2;           // row (0..63) this thread computes w for
    const int jb = (t & 3) * 8;      // j-offset within tile for w-compute
    const float maxdv = maxd[0];
    const float src_r = src[i0 + wr];
    const float e0 = src_r + maxdv;
    const float m_r = e0 > 0.f ? e0 : ALPHA * e0;   // per-row softmax shift (>= row max)
    float den_acc = 0.f;
    float4 acc[16];
    #pragma unroll
    for (int k = 0; k < 16; ++k) acc[k] = make_float4(0.f, 0.f, 0.f, 0.f);

    for (int jt = 0; jt < jseg; jt += 32) {
        const int j0 = jbeg + jt;
        __syncthreads();
        // stage h tile (coalesced float4)
        #pragma unroll
        for (int i2 = 0; i2 < 8; ++i2) {
            int f = i2 * 256 + t;
            int r = f >> 6;
            int c4 = (f & 63) << 2;
            *(float4*)&hs[r][c4] = *(const float4*)&h[(size_t)(j0 + r) * FF + c4];
        }
        // compute w tile: w = adj ? exp(lrelu(src+dst) - m) : 0
        {
            const size_t arow = (size_t)(i0 + wr) * NN + j0 + jb;
            const int4 a0 = *(const int4*)&adj[arow];
            const int4 a1 = *(const int4*)&adj[arow + 4];
            const float4 d0 = *(const float4*)&dst[j0 + jb];
            const float4 d1 = *(const float4*)&dst[j0 + jb + 4];
            int av[8] = {a0.x, a0.y, a0.z, a0.w, a1.x, a1.y, a1.z, a1.w};
            float dv[8] = {d0.x, d0.y, d0.z, d0.w, d1.x, d1.y, d1.z, d1.w};
            #pragma unroll
            for (int u = 0; u < 8; ++u) {
                float e = src_r + dv[u];
                e = e > 0.f ? e : ALPHA * e;
                float w = (av[u] > 0) ? __expf(e - m_r) : 0.f;
                wT[jb + u][wr] = w;
                den_acc += w;
            }
        }
        __syncthreads();
        // register-tiled FMA: wave wv -> rows wv*16..+15, lane l -> cols 4l..4l+3
        #pragma unroll 4
        for (int j = 0; j < 32; ++j) {
            float4 hv = *(float4*)&hs[j][l << 2];
            #pragma unroll
            for (int m4 = 0; m4 < 4; ++m4) {
                float4 w4 = *(float4*)&wT[j][wv * 16 + m4 * 4];
                acc[m4 * 4 + 0].x += w4.x * hv.x; acc[m4 * 4 + 0].y += w4.x * hv.y;
                acc[m4 * 4 + 0].z += w4.x * hv.z; acc[m4 * 4 + 0].w += w4.x * hv.w;
                acc[m4 * 4 + 1].x += w4.y * hv.x; acc[m4 * 4 + 1].y += w4.y * hv.y;
                acc[m4 * 4 + 1].z += w4.y * hv.z; acc[m4 * 4 + 1].w += w4.y * hv.w;
                acc[m4 * 4 + 2].x += w4.z * hv.x; acc[m4 * 4 + 2].y += w4.z * hv.y;
                acc[m4 * 4 + 2].z += w4.z * hv.z; acc[m4 * 4 + 2].w += w4.z * hv.w;
                acc[m4 * 4 + 3].x += w4.w * hv.x; acc[m4 * 4 + 3].y += w4.w * hv.y;
                acc[m4 * 4 + 3].z += w4.w * hv.z; acc[m4 * 4 + 3].w += w4.w * hv.w;
            }
        }
    }
    // write partial numerators (coalesced float4)
    #pragma unroll
    for (int k = 0; k < 16; ++k) {
        *(float4*)&num[((size_t)seg * NN + i0 + wv * 16 + k) * FF + (l << 2)] = acc[k];
    }
    // partial denominators
    dl[wr][t & 3] = den_acc;
    __syncthreads();
    if (t < 64) den[(size_t)seg * NN + i0 + t] = dl[t][0] + dl[t][1] + dl[t][2] + dl[t][3];
}

// ---------------- K4: out = relu( sum_s num / sum_s den ) -----------------
__global__ __launch_bounds__(256) void k4_out(const float* __restrict__ num,
                                              const float* __restrict__ den,
                                              float* __restrict__ out, int S) {
    size_t f4 = (size_t)blockIdx.x * 256 + threadIdx.x;  // float4 index over N*F/4
    int i = (int)(f4 >> 6);
    int c4 = (int)(f4 & 63) << 2;
    float4 s = make_float4(0.f, 0.f, 0.f, 0.f);
    float d = 0.f;
    for (int sg = 0; sg < S; ++sg) {
        float4 v = *(const float4*)&num[((size_t)sg * NN + i) * FF + c4];
        s.x += v.x; s.y += v.y; s.z += v.z; s.w += v.w;
        d += den[(size_t)sg * NN + i];
    }
    float inv = 1.f / d;
    float4 o;
    o.x = fmaxf(s.x * inv, 0.f);
    o.y = fmaxf(s.y * inv, 0.f);
    o.z = fmaxf(s.z * inv, 0.f);
    o.w = fmaxf(s.w * inv, 0.f);
    *(float4*)&out[(size_t)i * FF + c4] = o;
}

extern "C" void kernel_launch(void* const* d_in, const int* in_sizes, int n_in,
                              void* d_out, int out_size, void* d_ws, size_t ws_size,
                              hipStream_t stream) {
    const float* X  = (const float*)d_in[0];
    const int*  adj = (const int*)d_in[1];
    const float* W  = (const float*)d_in[2];
    const float* a  = (const float*)d_in[3];
    float* out = (float*)d_out;
    float* ws = (float*)d_ws;

    // workspace layout (floats)
    const size_t off_h    = 0;
    const size_t off_src  = off_h + (size_t)NN * FF;       // 2097152
    const size_t off_dst  = off_src + NN;
    const size_t off_maxd = off_dst + NN;
    const size_t off_num  = off_maxd + 16;                  // 16B-aligned

    // pick segment count S that fits in ws
    int S = 4;
    while (S > 1) {
        size_t need = (off_num + (size_t)S * NN * FF + (size_t)S * NN) * sizeof(float);
        if (need <= ws_size) break;
        S >>= 1;
    }
    const size_t off_den = off_num + (size_t)S * NN * FF;

    float* h_ws   = ws + off_h;
    float* src_ws = ws + off_src;
    float* dst_ws = ws + off_dst;
    float* maxd   = ws + off_maxd;
    float* num_ws = ws + off_num;
    float* den_ws = ws + off_den;

    k1_xw<<<NN / 32, 256, 0, stream>>>(X, W, h_ws);
    k2_srcdst<<<NN / 4, 256, 0, stream>>>(h_ws, a, src_ws, dst_ws);
    k2b_max<<<1, 256, 0, stream>>>(dst_ws, maxd);
    k3_attn<<<(NN / 64) * S, 256, 0, stream>>>(adj, h_ws, src_ws, dst_ws, maxd,
                                               num_ws, den_ws, S);
    k4_out<<<(NN * FF / 4) / 256, 256, 0, stream>>>(num_ws, den_ws, out, S);
}

// Round 2
// 540.665 us; speedup vs baseline: 1.5564x; 1.5564x over previous
//
#include <hip/hip_runtime.h>
#include <math.h>

#define NN 8192
#define FF 256
#define ALPHA 0.2f
#define JT 32            // k-step (j per tile)
#define LP 40            // padded LDS row (elems): 80 B = 16B-aligned, bank-balanced

typedef __bf16 bf16x8 __attribute__((ext_vector_type(8)));
typedef float  f32x4  __attribute__((ext_vector_type(4)));

// ---------------- K1: h = X @ W (fp32) ------------------------------------
__global__ __launch_bounds__(256) void k1_xw(const float* __restrict__ X,
                                             const float* __restrict__ W,
                                             float* __restrict__ h) {
    __shared__ float xs[32][FF];
    const int t = threadIdx.x;
    const int i0 = blockIdx.x * 32;
    #pragma unroll
    for (int it = 0; it < 8; ++it) {
        int f = it * 256 + t;
        int r = f >> 6;
        int c4 = (f & 63) << 2;
        *(float4*)&xs[r][c4] = *(const float4*)&X[(size_t)(i0 + r) * FF + c4];
    }
    __syncthreads();
    float acc[32];
    #pragma unroll
    for (int r = 0; r < 32; ++r) acc[r] = 0.f;
    for (int kt = 0; kt < FF; kt += 8) {
        float wk[8];
        #pragma unroll
        for (int u = 0; u < 8; ++u) wk[u] = W[(size_t)(kt + u) * FF + t];
        #pragma unroll
        for (int r = 0; r < 32; ++r) {
            float4 xa = *(float4*)&xs[r][kt];
            float4 xb = *(float4*)&xs[r][kt + 4];
            acc[r] += xa.x * wk[0] + xa.y * wk[1] + xa.z * wk[2] + xa.w * wk[3]
                    + xb.x * wk[4] + xb.y * wk[5] + xb.z * wk[6] + xb.w * wk[7];
        }
    }
    #pragma unroll
    for (int r = 0; r < 32; ++r) h[(size_t)(i0 + r) * FF + t] = acc[r];
}

// ---------------- K1b: transpose + bf16 hi/lo split -----------------------
// hT layout: [2][FF][NN] bf16  (hl=0: hi, hl=1: lo)
__global__ __launch_bounds__(256) void k1b_split(const float* __restrict__ h,
                                                 __bf16* __restrict__ hT) {
    __shared__ float ts[64][65];
    const int t = threadIdx.x;
    const int j0 = blockIdx.x * 64;
    const int f0 = blockIdx.y * 64;
    #pragma unroll
    for (int r = 0; r < 4; ++r) {
        int jr = r * 16 + (t >> 4);
        int fc = (t & 15) * 4;
        *(float4*)&ts[jr][fc] = *(const float4*)&h[(size_t)(j0 + jr) * FF + f0 + fc];
    }
    __syncthreads();
    const int f = t >> 2;
    const int jc = (t & 3) * 16;
    union { bf16x8 v[2]; __bf16 e[16]; } hi, lo;
    #pragma unroll
    for (int u = 0; u < 16; ++u) {
        float x = ts[jc + u][f];
        __bf16 h1 = (__bf16)x;
        hi.e[u] = h1;
        lo.e[u] = (__bf16)(x - (float)h1);
    }
    size_t base = (size_t)(f0 + f) * NN + j0 + jc;
    *(bf16x8*)&hT[base]     = hi.v[0];
    *(bf16x8*)&hT[base + 8] = hi.v[1];
    size_t lbase = (size_t)FF * NN + base;
    *(bf16x8*)&hT[lbase]     = lo.v[0];
    *(bf16x8*)&hT[lbase + 8] = lo.v[1];
}

// ---------------- K2: src/dst projections ---------------------------------
__global__ __launch_bounds__(256) void k2_srcdst(const float* __restrict__ h,
                                                 const float* __restrict__ a,
                                                 float* __restrict__ src,
                                                 float* __restrict__ dst) {
    const int wv = threadIdx.x >> 6;
    const int l = threadIdx.x & 63;
    const int i = blockIdx.x * 4 + wv;
    float s = 0.f, d = 0.f;
    #pragma unroll
    for (int k = 0; k < 4; ++k) {
        float hv = h[(size_t)i * FF + l + 64 * k];
        s += hv * a[l + 64 * k];
        d += hv * a[FF + l + 64 * k];
    }
    #pragma unroll
    for (int off = 32; off > 0; off >>= 1) {
        s += __shfl_down(s, off);
        d += __shfl_down(d, off);
    }
    if (l == 0) { src[i] = s; dst[i] = d; }
}

// ---------------- K2b: global max of dst ----------------------------------
__global__ __launch_bounds__(256) void k2b_max(const float* __restrict__ dst,
                                               float* __restrict__ maxd) {
    __shared__ float red[256];
    float m = -1e30f;
    for (int i = threadIdx.x; i < NN; i += 256) m = fmaxf(m, dst[i]);
    red[threadIdx.x] = m;
    __syncthreads();
    for (int s = 128; s > 0; s >>= 1) {
        if (threadIdx.x < s) red[threadIdx.x] = fmaxf(red[threadIdx.x], red[threadIdx.x + s]);
        __syncthreads();
    }
    if (threadIdx.x == 0) maxd[0] = red[0];
}

// ---------------- K3: MFMA fused masked-softmax GEMM ----------------------
// Block: 64 i-rows x 256 f, 256 threads (4 waves; wave wv -> f in [wv*64, wv*64+64)).
// Per k-step (32 j): stage hT hi/lo tile -> LDS (B layout), compute w -> LDS
// (A layout), then 16x16x32 bf16 MFMAs, 2 passes (hi+lo) into fp32 acc.
__global__ __launch_bounds__(256) void k3_attn(const int* __restrict__ adj,
                                               const __bf16* __restrict__ hT,
                                               const float* __restrict__ src,
                                               const float* __restrict__ dst,
                                               const float* __restrict__ maxd,
                                               float* __restrict__ num,
                                               float* __restrict__ den,
                                               int S) {
    __shared__ __bf16 bh[2][FF][LP];   // 40960 B
    __shared__ __bf16 wA[64][LP];      //  5120 B
    __shared__ float dl[64][4];        //  1024 B
    const int t = threadIdx.x;
    const int nIt = NN / 64;
    const int it = blockIdx.x % nIt;
    const int seg = blockIdx.x / nIt;
    const int i0 = it * 64;
    const int jseg = NN / S;
    const int jbeg = seg * jseg;
    // phase-1 (w compute) mapping: thread -> (row p_i, 8-j chunk p_q)
    const int p_i = t >> 2;
    const int p_q = t & 3;
    const float maxdv = maxd[0];
    const float src_r = src[i0 + p_i];
    const float e0 = src_r + maxdv;
    const float m_r = e0 > 0.f ? e0 : ALPHA * e0;  // per-row softmax shift >= row max
    float den_reg = 0.f;
    // phase-2 (MFMA) mapping
    const int wv = t >> 6;
    const int l = t & 63;
    const int ln = l & 15;
    const int g = l >> 4;
    f32x4 acc[4][4];
    #pragma unroll
    for (int mt = 0; mt < 4; ++mt)
        #pragma unroll
        for (int nt = 0; nt < 4; ++nt)
            acc[mt][nt] = (f32x4){0.f, 0.f, 0.f, 0.f};

    for (int jt = 0; jt < jseg; jt += JT) {
        const int j0 = jbeg + jt;
        __syncthreads();
        // (a) stage h hi/lo tiles: 2*256 rows x 32 j, bf16x8 chunks
        #pragma unroll
        for (int r = 0; r < 8; ++r) {
            int c = t + r * 256;        // 0..2047 = hl*1024 + f*4 + jc
            int jc = c & 3;
            int f = (c >> 2) & 255;
            int hl = c >> 10;
            bf16x8 v = *(const bf16x8*)&hT[((size_t)hl * FF + f) * NN + j0 + jc * 8];
            *(bf16x8*)&bh[hl][f][jc * 8] = v;
        }
        // (b) w tile: w = adj ? exp(lrelu(src+dst) - m) : 0, in A-frag layout
        {
            const int* ap = adj + (size_t)(i0 + p_i) * NN + j0 + p_q * 8;
            const int4 a0 = *(const int4*)ap;
            const int4 a1 = *(const int4*)(ap + 4);
            const float* dp = dst + j0 + p_q * 8;
            const float4 d0 = *(const float4*)dp;
            const float4 d1 = *(const float4*)(dp + 4);
            const int av[8] = {a0.x, a0.y, a0.z, a0.w, a1.x, a1.y, a1.z, a1.w};
            const float dv[8] = {d0.x, d0.y, d0.z, d0.w, d1.x, d1.y, d1.z, d1.w};
            union { bf16x8 v; __bf16 e[8]; } wu;
            #pragma unroll
            for (int u = 0; u < 8; ++u) {
                float e = src_r + dv[u];
                e = e > 0.f ? e : ALPHA * e;
                float w = (av[u] > 0) ? __expf(e - m_r) : 0.f;
                den_reg += w;
                wu.e[u] = (__bf16)w;
            }
            *(bf16x8*)&wA[p_i][p_q * 8] = wu.v;
        }
        __syncthreads();
        // (c) MFMA: A[m=ln][k=g*8+idx] from wA, B[k][n=ln] from bh (transposed h)
        bf16x8 af[4];
        #pragma unroll
        for (int mt = 0; mt < 4; ++mt) af[mt] = *(bf16x8*)&wA[mt * 16 + ln][g * 8];
        #pragma unroll
        for (int nt = 0; nt < 4; ++nt) {
            #pragma unroll
            for (int hl = 0; hl < 2; ++hl) {
                bf16x8 bfr = *(bf16x8*)&bh[hl][wv * 64 + nt * 16 + ln][g * 8];
                #pragma unroll
                for (int mt = 0; mt < 4; ++mt)
                    acc[mt][nt] = __builtin_amdgcn_mfma_f32_16x16x32_bf16(
                        af[mt], bfr, acc[mt][nt], 0, 0, 0);
            }
        }
    }
    // epilogue: C layout col=lane&15, row=(lane>>4)*4+reg
    #pragma unroll
    for (int mt = 0; mt < 4; ++mt)
        #pragma unroll
        for (int nt = 0; nt < 4; ++nt)
            #pragma unroll
            for (int rg = 0; rg < 4; ++rg)
                num[((size_t)seg * NN + i0 + mt * 16 + g * 4 + rg) * FF
                    + wv * 64 + nt * 16 + ln] = acc[mt][nt][rg];
    dl[p_i][p_q] = den_reg;
    __syncthreads();
    if (t < 64) den[(size_t)seg * NN + i0 + t] = dl[t][0] + dl[t][1] + dl[t][2] + dl[t][3];
}

// ---------------- K4: out = relu( sum_s num / sum_s den ) -----------------
__global__ __launch_bounds__(256) void k4_out(const float* __restrict__ num,
                                              const float* __restrict__ den,
                                              float* __restrict__ out, int S) {
    size_t f4 = (size_t)blockIdx.x * 256 + threadIdx.x;
    int i = (int)(f4 >> 6);
    int c4 = (int)(f4 & 63) << 2;
    float4 s = make_float4(0.f, 0.f, 0.f, 0.f);
    float d = 0.f;
    for (int sg = 0; sg < S; ++sg) {
        float4 v = *(const float4*)&num[((size_t)sg * NN + i) * FF + c4];
        s.x += v.x; s.y += v.y; s.z += v.z; s.w += v.w;
        d += den[(size_t)sg * NN + i];
    }
    float inv = 1.f / d;
    float4 o;
    o.x = fmaxf(s.x * inv, 0.f);
    o.y = fmaxf(s.y * inv, 0.f);
    o.z = fmaxf(s.z * inv, 0.f);
    o.w = fmaxf(s.w * inv, 0.f);
    *(float4*)&out[(size_t)i * FF + c4] = o;
}

extern "C" void kernel_launch(void* const* d_in, const int* in_sizes, int n_in,
                              void* d_out, int out_size, void* d_ws, size_t ws_size,
                              hipStream_t stream) {
    const float* X  = (const float*)d_in[0];
    const int*  adj = (const int*)d_in[1];
    const float* W  = (const float*)d_in[2];
    const float* a  = (const float*)d_in[3];
    float* out = (float*)d_out;
    char* ws = (char*)d_ws;

    // workspace layout (bytes)
    const size_t off_h    = 0;                                  // 8 MB fp32
    const size_t off_hT   = off_h + (size_t)NN * FF * 4;        // 8 MB bf16 [2][FF][NN]
    const size_t off_src  = off_hT + (size_t)2 * FF * NN * 2;   // 32 KB
    const size_t off_dst  = off_src + (size_t)NN * 4;           // 32 KB
    const size_t off_maxd = off_dst + (size_t)NN * 4;           // 64 B
    const size_t off_num  = off_maxd + 256;

    int S = 8;
    while (S > 1) {
        size_t need = off_num + (size_t)S * NN * FF * 4 + (size_t)S * NN * 4;
        if (need <= ws_size) break;
        S >>= 1;
    }
    const size_t off_den = off_num + (size_t)S * NN * FF * 4;

    float* h_ws   = (float*)(ws + off_h);
    __bf16* hT_ws = (__bf16*)(ws + off_hT);
    float* src_ws = (float*)(ws + off_src);
    float* dst_ws = (float*)(ws + off_dst);
    float* maxd   = (float*)(ws + off_maxd);
    float* num_ws = (float*)(ws + off_num);
    float* den_ws = (float*)(ws + off_den);

    k1_xw<<<NN / 32, 256, 0, stream>>>(X, W, h_ws);
    k1b_split<<<dim3(NN / 64, FF / 64), 256, 0, stream>>>(h_ws, hT_ws);
    k2_srcdst<<<NN / 4, 256, 0, stream>>>(h_ws, a, src_ws, dst_ws);
    k2b_max<<<1, 256, 0, stream>>>(dst_ws, maxd);
    k3_attn<<<(NN / 64) * S, 256, 0, stream>>>(adj, hT_ws, src_ws, dst_ws, maxd,
                                               num_ws, den_ws, S);
    k4_out<<<(NN * FF / 4) / 256, 256, 0, stream>>>(num_ws, den_ws, out, S);
}

// Round 3
// 481.933 us; speedup vs baseline: 1.7461x; 1.1219x over previous
//
#include <hip/hip_runtime.h>
#include <math.h>

#define NN 8192
#define FF 256
#define ALPHA 0.2f
#define SS 4                 // j-segments
#define JSEG (NN / SS)       // 2048
#define STEPS (JSEG / 32)    // 64

typedef __bf16 bf16x8 __attribute__((ext_vector_type(8)));
typedef __bf16 bf16x4 __attribute__((ext_vector_type(4)));
typedef float  f32x4  __attribute__((ext_vector_type(4)));

__device__ __forceinline__ void dma16(const void* g, void* l) {
    __builtin_amdgcn_global_load_lds((const __attribute__((address_space(1))) void*)g,
                                     (__attribute__((address_space(3))) void*)l,
                                     16, 0, 0);
}

// ---------------- K0: WT[hl][n][k] bf16 hi/lo from W[k][n] fp32 -----------
__global__ __launch_bounds__(256) void k0_wt(const float* __restrict__ W,
                                             __bf16* __restrict__ WT) {
    __shared__ float ts[64][65];
    const int t = threadIdx.x;
    const int k0 = blockIdx.x * 64;
    const int n0 = blockIdx.y * 64;
    #pragma unroll
    for (int r = 0; r < 4; ++r) {
        int krow = r * 16 + (t >> 4);
        int nc4 = (t & 15) * 4;
        *(float4*)&ts[krow][nc4] = *(const float4*)&W[(size_t)(k0 + krow) * FF + n0 + nc4];
    }
    __syncthreads();
    const int nloc = t >> 2;
    const int kc = (t & 3) * 16;
    union { bf16x8 v[2]; __bf16 e[16]; } hi, lo;
    #pragma unroll
    for (int u = 0; u < 16; ++u) {
        float x = ts[kc + u][nloc];
        __bf16 h1 = (__bf16)x;
        hi.e[u] = h1;
        lo.e[u] = (__bf16)(x - (float)h1);
    }
    size_t base = (size_t)(n0 + nloc) * FF + k0 + kc;
    *(bf16x8*)&WT[base] = hi.v[0];
    *(bf16x8*)&WT[base + 8] = hi.v[1];
    size_t lbase = (size_t)FF * FF + base;
    *(bf16x8*)&WT[lbase] = lo.v[0];
    *(bf16x8*)&WT[lbase + 8] = lo.v[1];
}

// ---------------- K1: MFMA h-tile -> hT(hi/lo, transposed) + src/dst ------
// Block: 32 i-rows x 256 f. h fp32 never hits HBM.
__global__ __launch_bounds__(256) void k1_h(const float* __restrict__ X,
                                            const __bf16* __restrict__ WT,
                                            const float* __restrict__ a,
                                            __bf16* __restrict__ hT,
                                            float* __restrict__ src,
                                            float* __restrict__ dst) {
    __shared__ __bf16 ax[2][32][40];
    __shared__ float hs[32][264];
    __shared__ float red[2][4][32];
    const int t = threadIdx.x;
    const int i0 = blockIdx.x * 32;
    const int l = t & 63, wv = t >> 6, ln = l & 15, g = l >> 4;
    f32x4 acc[2][4];
    #pragma unroll
    for (int mt = 0; mt < 2; ++mt)
        #pragma unroll
        for (int nt = 0; nt < 4; ++nt)
            acc[mt][nt] = (f32x4){0.f, 0.f, 0.f, 0.f};

    for (int ks = 0; ks < 8; ++ks) {
        const int k0 = ks * 32;
        {   // stage X tile as hi/lo bf16
            int row = t >> 3, c4 = (t & 7) * 4;
            float4 xv = *(const float4*)&X[(size_t)(i0 + row) * FF + k0 + c4];
            bf16x4 hi4, lo4;
            float xs_[4] = {xv.x, xv.y, xv.z, xv.w};
            #pragma unroll
            for (int u = 0; u < 4; ++u) {
                __bf16 h1 = (__bf16)xs_[u];
                hi4[u] = h1;
                lo4[u] = (__bf16)(xs_[u] - (float)h1);
            }
            *(bf16x4*)&ax[0][row][c4] = hi4;
            *(bf16x4*)&ax[1][row][c4] = lo4;
        }
        __syncthreads();
        bf16x8 ah[2], al[2];
        ah[0] = *(bf16x8*)&ax[0][ln][g * 8];
        ah[1] = *(bf16x8*)&ax[0][16 + ln][g * 8];
        al[0] = *(bf16x8*)&ax[1][ln][g * 8];
        al[1] = *(bf16x8*)&ax[1][16 + ln][g * 8];
        #pragma unroll
        for (int nt = 0; nt < 4; ++nt) {
            const int n = wv * 64 + nt * 16 + ln;
            bf16x8 bh8 = *(const bf16x8*)&WT[(size_t)n * FF + k0 + g * 8];
            bf16x8 bl8 = *(const bf16x8*)&WT[(size_t)(FF + n) * FF + k0 + g * 8];
            #pragma unroll
            for (int mt = 0; mt < 2; ++mt) {
                acc[mt][nt] = __builtin_amdgcn_mfma_f32_16x16x32_bf16(ah[mt], bh8, acc[mt][nt], 0, 0, 0);
                acc[mt][nt] = __builtin_amdgcn_mfma_f32_16x16x32_bf16(ah[mt], bl8, acc[mt][nt], 0, 0, 0);
                acc[mt][nt] = __builtin_amdgcn_mfma_f32_16x16x32_bf16(al[mt], bh8, acc[mt][nt], 0, 0, 0);
            }
        }
        __syncthreads();
    }
    // dump to LDS + src/dst partials
    float an[4], ad[4];
    #pragma unroll
    for (int nt = 0; nt < 4; ++nt) {
        an[nt] = a[wv * 64 + nt * 16 + ln];
        ad[nt] = a[FF + wv * 64 + nt * 16 + ln];
    }
    float sp[2][4], dp[2][4];
    #pragma unroll
    for (int mt = 0; mt < 2; ++mt)
        #pragma unroll
        for (int rg = 0; rg < 4; ++rg) { sp[mt][rg] = 0.f; dp[mt][rg] = 0.f; }
    #pragma unroll
    for (int mt = 0; mt < 2; ++mt)
        #pragma unroll
        for (int nt = 0; nt < 4; ++nt)
            #pragma unroll
            for (int rg = 0; rg < 4; ++rg) {
                float v = acc[mt][nt][rg];
                hs[mt * 16 + g * 4 + rg][wv * 64 + nt * 16 + ln] = v;
                sp[mt][rg] += v * an[nt];
                dp[mt][rg] += v * ad[nt];
            }
    #pragma unroll
    for (int mk = 1; mk < 16; mk <<= 1)
        #pragma unroll
        for (int mt = 0; mt < 2; ++mt)
            #pragma unroll
            for (int rg = 0; rg < 4; ++rg) {
                sp[mt][rg] += __shfl_xor(sp[mt][rg], mk);
                dp[mt][rg] += __shfl_xor(dp[mt][rg], mk);
            }
    if (ln == 0) {
        #pragma unroll
        for (int mt = 0; mt < 2; ++mt)
            #pragma unroll
            for (int rg = 0; rg < 4; ++rg) {
                red[0][wv][mt * 16 + g * 4 + rg] = sp[mt][rg];
                red[1][wv][mt * 16 + g * 4 + rg] = dp[mt][rg];
            }
    }
    __syncthreads();
    if (t < 32) {
        src[i0 + t] = red[0][0][t] + red[0][1][t] + red[0][2][t] + red[0][3][t];
        dst[i0 + t] = red[1][0][t] + red[1][1][t] + red[1][2][t] + red[1][3][t];
    }
    // transpose-out hT hi/lo (plain [hl][f][j] layout)
    {
        const int f = t;
        #pragma unroll
        for (int jc = 0; jc < 4; ++jc) {
            union { bf16x8 v; __bf16 e[8]; } hi, lo;
            #pragma unroll
            for (int u = 0; u < 8; ++u) {
                float x = hs[jc * 8 + u][f];
                __bf16 h1 = (__bf16)x;
                hi.e[u] = h1;
                lo.e[u] = (__bf16)(x - (float)h1);
            }
            *(bf16x8*)&hT[(size_t)f * NN + i0 + jc * 8] = hi.v;
            *(bf16x8*)&hT[(size_t)(FF + f) * NN + i0 + jc * 8] = lo.v;
        }
    }
}

// ---------------- K2b: maxd = max_j dst_j ---------------------------------
__global__ __launch_bounds__(256) void k2b_max(const float* __restrict__ dst,
                                               float* __restrict__ maxd) {
    __shared__ float red[256];
    float m = -1e30f;
    #pragma unroll
    for (int r = 0; r < NN / 1024; ++r) {
        float4 v = *(const float4*)&dst[(r * 256 + threadIdx.x) * 4];
        m = fmaxf(m, fmaxf(fmaxf(v.x, v.y), fmaxf(v.z, v.w)));
    }
    red[threadIdx.x] = m;
    __syncthreads();
    for (int s = 128; s > 0; s >>= 1) {
        if (threadIdx.x < s) red[threadIdx.x] = fmaxf(red[threadIdx.x], red[threadIdx.x + s]);
        __syncthreads();
    }
    if (threadIdx.x == 0) maxd[0] = red[0];
}

// ---------------- K3: pipelined MFMA fused masked-softmax GEMM ------------
// M=64 rows x F=256, 32-j steps, dbuf LDS, one barrier/step, DMA staging.
__global__ __launch_bounds__(256, 2) void k3_attn(const int* __restrict__ adj,
                                                  const __bf16* __restrict__ hT,
                                                  const float* __restrict__ src,
                                                  const float* __restrict__ dst,
                                                  const float* __restrict__ maxd,
                                                  float* __restrict__ num,
                                                  float* __restrict__ den) {
    __shared__ __bf16 bh[2][2048 * 8];   // [buf][chunk(hl,f,pc)*8]  2 x 32 KB
    __shared__ __bf16 wA[2][64][40];     // dbuf A-tiles, padded      2 x 5 KB
    __shared__ float dl[64][4];
    const int t = threadIdx.x;
    const int l = t & 63, wv = t >> 6, ln = l & 15, g = l >> 4;
    const int it = blockIdx.x & 127;
    const int seg = blockIdx.x >> 7;
    const int i0 = it * 64;
    const int jbeg = seg * JSEG;
    const int p_i = t >> 2, p_q = t & 3;
    const float maxdv = maxd[0];
    const float src_r = src[i0 + p_i];
    const float e0 = src_r + maxdv;
    const float m_r = e0 > 0.f ? e0 : ALPHA * e0;

    // DMA descriptors: lane-linear LDS chunks, swizzle applied on global addr
    int rowbase[8], cb[8];
    #pragma unroll
    for (int r = 0; r < 8; ++r) {
        int cbase = r * 256 + wv * 64;
        int c = cbase + l;
        int hl = c >> 10;
        int f = (c >> 2) & 255;
        int pc = c & 3;
        int jc = pc ^ ((f >> 1) & 3);
        rowbase[r] = (hl * FF + f) * NN + jc * 8;
        cb[r] = __builtin_amdgcn_readfirstlane(cbase);
    }
    const int* arow = adj + (size_t)(i0 + p_i) * NN + p_q * 8;

    // prologue: prefetch step 0
    #pragma unroll
    for (int r = 0; r < 8; ++r)
        dma16(&hT[rowbase[r] + jbeg], &bh[0][cb[r] * 8]);
    int4 a0 = *(const int4*)(arow + jbeg);
    int4 a1 = *(const int4*)(arow + jbeg + 4);
    float4 d0 = *(const float4*)&dst[jbeg + p_q * 8];
    float4 d1 = *(const float4*)&dst[jbeg + p_q * 8 + 4];

    float den_reg = 0.f;
    f32x4 acc[4][4];
    #pragma unroll
    for (int mt = 0; mt < 4; ++mt)
        #pragma unroll
        for (int nt = 0; nt < 4; ++nt)
            acc[mt][nt] = (f32x4){0.f, 0.f, 0.f, 0.f};

    for (int s = 0; s < STEPS; ++s) {
        const int cur = s & 1;
        {   // A: w(s) from prefetched regs -> wA[cur]
            const int av[8] = {a0.x, a0.y, a0.z, a0.w, a1.x, a1.y, a1.z, a1.w};
            const float dv[8] = {d0.x, d0.y, d0.z, d0.w, d1.x, d1.y, d1.z, d1.w};
            union { bf16x8 v; __bf16 e[8]; } wu;
            #pragma unroll
            for (int u = 0; u < 8; ++u) {
                float e = src_r + dv[u];
                e = e > 0.f ? e : ALPHA * e;
                float w = (av[u] > 0) ? __expf(e - m_r) : 0.f;
                den_reg += w;
                wu.e[u] = (__bf16)w;
            }
            *(bf16x8*)&wA[cur][p_i][p_q * 8] = wu.v;
        }
        __syncthreads();   // drains DMA(s) (in flight one full iter) + wA writes
        if (s + 1 < STEPS) {  // C: prefetch s+1 (stays in flight past MFMA)
            const int j1 = jbeg + (s + 1) * 32;
            #pragma unroll
            for (int r = 0; r < 8; ++r)
                dma16(&hT[rowbase[r] + j1], &bh[cur ^ 1][cb[r] * 8]);
            a0 = *(const int4*)(arow + j1);
            a1 = *(const int4*)(arow + j1 + 4);
            d0 = *(const float4*)&dst[j1 + p_q * 8];
            d1 = *(const float4*)&dst[j1 + p_q * 8 + 4];
        }
        // D: MFMA on bh[cur], wA[cur]
        bf16x8 af[4];
        #pragma unroll
        for (int mt = 0; mt < 4; ++mt)
            af[mt] = *(bf16x8*)&wA[cur][mt * 16 + ln][g * 8];
        #pragma unroll
        for (int nt = 0; nt < 4; ++nt) {
            const int f = wv * 64 + nt * 16 + ln;
            const int sw = (f >> 1) & 3;
            #pragma unroll
            for (int hl = 0; hl < 2; ++hl) {
                const int chunk = (hl * FF + f) * 4 + (g ^ sw);
                bf16x8 bfr = *(bf16x8*)&bh[cur][chunk * 8];
                #pragma unroll
                for (int mt = 0; mt < 4; ++mt)
                    acc[mt][nt] = __builtin_amdgcn_mfma_f32_16x16x32_bf16(
                        af[mt], bfr, acc[mt][nt], 0, 0, 0);
            }
        }
    }
    // epilogue
    #pragma unroll
    for (int mt = 0; mt < 4; ++mt)
        #pragma unroll
        for (int nt = 0; nt < 4; ++nt)
            #pragma unroll
            for (int rg = 0; rg < 4; ++rg)
                num[((size_t)seg * NN + i0 + mt * 16 + g * 4 + rg) * FF
                    + wv * 64 + nt * 16 + ln] = acc[mt][nt][rg];
    dl[p_i][p_q] = den_reg;
    __syncthreads();
    if (t < 64) den[(size_t)seg * NN + i0 + t] = dl[t][0] + dl[t][1] + dl[t][2] + dl[t][3];
}

// ---------------- K4: out = relu( sum_s num / sum_s den ) -----------------
__global__ __launch_bounds__(256) void k4_out(const float* __restrict__ num,
                                              const float* __restrict__ den,
                                              float* __restrict__ out) {
    size_t f4 = (size_t)blockIdx.x * 256 + threadIdx.x;
    int i = (int)(f4 >> 6);
    int c4 = (int)(f4 & 63) << 2;
    float4 s = make_float4(0.f, 0.f, 0.f, 0.f);
    float d = 0.f;
    #pragma unroll
    for (int sg = 0; sg < SS; ++sg) {
        float4 v = *(const float4*)&num[((size_t)sg * NN + i) * FF + c4];
        s.x += v.x; s.y += v.y; s.z += v.z; s.w += v.w;
        d += den[(size_t)sg * NN + i];
    }
    float inv = 1.f / d;
    float4 o;
    o.x = fmaxf(s.x * inv, 0.f);
    o.y = fmaxf(s.y * inv, 0.f);
    o.z = fmaxf(s.z * inv, 0.f);
    o.w = fmaxf(s.w * inv, 0.f);
    *(float4*)&out[(size_t)i * FF + c4] = o;
}

extern "C" void kernel_launch(void* const* d_in, const int* in_sizes, int n_in,
                              void* d_out, int out_size, void* d_ws, size_t ws_size,
                              hipStream_t stream) {
    const float* X  = (const float*)d_in[0];
    const int*  adj = (const int*)d_in[1];
    const float* W  = (const float*)d_in[2];
    const float* a  = (const float*)d_in[3];
    float* out = (float*)d_out;
    char* ws = (char*)d_ws;

    // workspace layout (bytes)
    const size_t off_hT   = 0;                                   // 8 MB bf16 [2][FF][NN]
    const size_t off_wt   = off_hT + (size_t)2 * FF * NN * 2;    // 256 KB bf16 [2][FF][FF]
    const size_t off_src  = off_wt + (size_t)2 * FF * FF * 2;
    const size_t off_dst  = off_src + (size_t)NN * 4;
    const size_t off_maxd = off_dst + (size_t)NN * 4;
    const size_t off_num  = off_maxd + 256;                      // 32 MB fp32 [SS][NN][FF]
    const size_t off_den  = off_num + (size_t)SS * NN * FF * 4;

    __bf16* hT_ws = (__bf16*)(ws + off_hT);
    __bf16* wt_ws = (__bf16*)(ws + off_wt);
    float* src_ws = (float*)(ws + off_src);
    float* dst_ws = (float*)(ws + off_dst);
    float* maxd   = (float*)(ws + off_maxd);
    float* num_ws = (float*)(ws + off_num);
    float* den_ws = (float*)(ws + off_den);

    k0_wt<<<dim3(FF / 64, FF / 64), 256, 0, stream>>>(W, wt_ws);
    k1_h<<<NN / 32, 256, 0, stream>>>(X, wt_ws, a, hT_ws, src_ws, dst_ws);
    k2b_max<<<1, 256, 0, stream>>>(dst_ws, maxd);
    k3_attn<<<(NN / 64) * SS, 256, 0, stream>>>(adj, hT_ws, src_ws, dst_ws, maxd,
                                                num_ws, den_ws);
    k4_out<<<(NN * FF / 4) / 256, 256, 0, stream>>>(num_ws, den_ws, out);
}